// Round 9
// baseline (125.439 us; speedup 1.0000x reference)
//
#include <hip/hip_runtime.h>

#define SMOOTH_F 1e-7f

typedef float f32x4 __attribute__((ext_vector_type(4)));
typedef float f32x2 __attribute__((ext_vector_type(2)));

constexpr int B = 8, C = 12, S = 4, H = 512, W = 512;
constexpr int HW    = H * W;          // 262144 = 2^18
constexpr int NPIX  = B * HW;         // 2097152
constexpr int QUADS = NPIX / 4;       // 524288
constexpr int BLOCK = 256;
constexpr int GRID  = QUADS / BLOCK;  // 2048, 1 quad/thread
constexpr int N     = B * C * HW;     // fc / oh element count

// sums layout in d_ws (floats):
// [0..3]   interS   [4..7]  isumS   [8..11]  tsumS
// [12..23] interC   [24..35] isumC  [36..47] tsumC
constexpr int NSUMS = 48;

// lb note: this source at (256,4) compiles to 60 VGPR with batched loads and
// block-contiguous NT store streams (88.4us, WRITE=202MB ideal). This round:
// (256,6) -- cap 85 > 60, testing whether occupancy rises to ~52% with the
// schedule intact. Block-edge LDS exchange (not wave-local) is load-bearing:
// it keeps NT write-combining streams 4KB-contiguous per block/channel.
__global__ __launch_bounds__(BLOCK, 6) void fused_kernel(
    const float* __restrict__ ss,   // [B,S,H,W]
    const float* __restrict__ cs,   // [B,C,H,W]
    const int*   __restrict__ tgt,  // [B,H,W]
    const int*   __restrict__ s2s,  // [C]
    float* __restrict__ outp,       // raw d_out: [loss, fc(N), oh(N)]
    float* __restrict__ sums)       // [48]
{
    const int q   = blockIdx.x * BLOCK + threadIdx.x; // quad index
    const int p   = q << 2;
    const int b   = p >> 18;          // p / HW
    const int rem = p & (HW - 1);
    const int lane = threadIdx.x & 63;
    const int wv   = threadIdx.x >> 6;

    // ---- targets + super-targets ----
    const int4 t4 = *reinterpret_cast<const int4*>(tgt + p);
    const int t[4] = {t4.x, t4.y, t4.z, t4.w};
    int st[4];
    #pragma unroll
    for (int i = 0; i < 4; i++) st[i] = s2s[t[i]];

    // ---- superclass channels: cache + accumulate ----
    float interS[S], isumS[S];
    int   tS[S], tC[C];
    float ssv[S][4];
    #pragma unroll
    for (int s = 0; s < S; s++) {
        const float4 v = *reinterpret_cast<const float4*>(ss + (b * S + s) * HW + rem);
        ssv[s][0] = v.x; ssv[s][1] = v.y; ssv[s][2] = v.z; ssv[s][3] = v.w;
        isumS[s] = v.x + v.y + v.z + v.w;
        interS[s] = 0.f; tS[s] = 0;
        #pragma unroll
        for (int i = 0; i < 4; i++) {
            const bool m = (st[i] == s);
            interS[s] += m ? ssv[s][i] : 0.f;
            tS[s] += (int)__popcll(__ballot(m));
        }
    }

    // ---- class channels: batched loads ----
    float cv[C][4];
    #pragma unroll
    for (int c = 0; c < C; c++) {
        const float4 v = *reinterpret_cast<const float4*>(cs + (b * C + c) * HW + rem);
        cv[c][0] = v.x; cv[c][1] = v.y; cv[c][2] = v.z; cv[c][3] = v.w;
    }

    // ---- phase A: wave-edge values (lane63's fc3/oh3) into LDS ----
    __shared__ float edge[BLOCK / 64][C][2];
    if (lane == 63) {
        #pragma unroll
        for (int c = 0; c < C; c++) {
            const int sup = s2s[c];
            const float sv3 = (sup == 0) ? ssv[0][3]
                            : (sup == 1) ? ssv[1][3]
                            : (sup == 2) ? ssv[2][3]
                            :              ssv[3][3];
            edge[wv][c][0] = cv[c][3] * sv3;
            edge[wv][c][1] = (t[3] == c) ? 1.f : 0.f;
        }
    }
    __syncthreads();

    // ---- phase C: per-channel compute + aligned NT stores ----
    // Shifted window: outp[J+k] holds fc element J-1+k (the +1 loss offset).
    // Threads 1..255 store dwordx4 at J (lead value via shfl_up, lane0 of
    // wv>0 pulls it from edge LDS); thread 0 stores the 3 leading elements;
    // thread 255 stores the trailing element. Exactly-once, all x4 aligned,
    // block-contiguous 4KB NT streams per channel.
    float interC[C], isumC[C];
    #pragma unroll
    for (int c = 0; c < C; c++) {
        const int J   = (b * C + c) * HW + rem;
        const int sup = s2s[c];
        isumC[c] = cv[c][0] + cv[c][1] + cv[c][2] + cv[c][3];
        interC[c] = 0.f; tC[c] = 0;
        float fc[4], oh[4];
        #pragma unroll
        for (int i = 0; i < 4; i++) {
            const bool eq = (t[i] == c);
            const float sv = (sup == 0) ? ssv[0][i]
                           : (sup == 1) ? ssv[1][i]
                           : (sup == 2) ? ssv[2][i]
                           :              ssv[3][i];
            oh[i] = eq ? 1.f : 0.f;
            fc[i] = cv[c][i] * sv;
            interC[c] += eq ? cv[c][i] : 0.f;
            tC[c] += (int)__popcll(__ballot(eq));
        }
        float pfc = __shfl_up(fc[3], 1);
        float poh = __shfl_up(oh[3], 1);
        if (lane == 0 && wv > 0) { pfc = edge[wv - 1][c][0]; poh = edge[wv - 1][c][1]; }

        if (threadIdx.x != 0) {
            const f32x4 vfc = {pfc, fc[0], fc[1], fc[2]};
            const f32x4 voh = {poh, oh[0], oh[1], oh[2]};
            __builtin_nontemporal_store(vfc, reinterpret_cast<f32x4*>(outp + J));
            __builtin_nontemporal_store(voh, reinterpret_cast<f32x4*>(outp + N + J));
        } else {
            __builtin_nontemporal_store(fc[0], outp + J + 1);
            __builtin_nontemporal_store((f32x2){fc[1], fc[2]}, reinterpret_cast<f32x2*>(outp + J + 2));
            __builtin_nontemporal_store(oh[0], outp + N + J + 1);
            __builtin_nontemporal_store((f32x2){oh[1], oh[2]}, reinterpret_cast<f32x2*>(outp + N + J + 2));
        }
        if (threadIdx.x == BLOCK - 1) {
            __builtin_nontemporal_store(fc[3], outp + J + 4);
            __builtin_nontemporal_store(oh[3], outp + N + J + 4);
        }
    }

    // ---- block reduction: 32 float partials + 16 uniform counts ----
    float vals[32];
    #pragma unroll
    for (int s = 0; s < S; s++) { vals[s] = interS[s]; vals[4 + s] = isumS[s]; }
    #pragma unroll
    for (int c = 0; c < C; c++) { vals[8 + c] = interC[c]; vals[20 + c] = isumC[c]; }

    __shared__ float red[BLOCK / 64][NSUMS];
    #pragma unroll
    for (int k = 0; k < 32; k++) {
        float v = vals[k];
        #pragma unroll
        for (int o = 32; o > 0; o >>= 1) v += __shfl_xor(v, o, 64);
        if (lane == 0) {
            const int idx = (k < 8) ? k : (k < 20) ? (12 + (k - 8)) : (24 + (k - 20));
            red[wv][idx] = v;
        }
    }
    if (lane == 0) {
        #pragma unroll
        for (int s = 0; s < S; s++) red[wv][8 + s]  = (float)tS[s];
        #pragma unroll
        for (int c = 0; c < C; c++) red[wv][36 + c] = (float)tC[c];
    }
    __syncthreads();
    if (threadIdx.x < NSUMS) {
        const float sblk = red[0][threadIdx.x] + red[1][threadIdx.x]
                         + red[2][threadIdx.x] + red[3][threadIdx.x];
        atomicAdd(&sums[threadIdx.x], sblk);
    }
}

__global__ void loss_kernel(const float* __restrict__ sums,
                            const float* __restrict__ w,
                            float* __restrict__ out)
{
    if (threadIdx.x == 0 && blockIdx.x == 0) {
        float superL = 0.f;
        #pragma unroll
        for (int s = 0; s < S; s++)
            superL += 1.f - (2.f * sums[s] + SMOOTH_F) / (sums[4 + s] + sums[8 + s] + SMOOTH_F);
        float finalL = 0.f, wsum = 0.f;
        #pragma unroll
        for (int c = 0; c < C; c++) {
            wsum   += w[c];
            finalL += w[c] * (1.f - (2.f * sums[12 + c] + SMOOTH_F) / (sums[24 + c] + sums[36 + c] + SMOOTH_F));
        }
        out[0] = 0.1f * superL / (float)S + finalL / wsum;
    }
}

extern "C" void kernel_launch(void* const* d_in, const int* in_sizes, int n_in,
                              void* d_out, int out_size, void* d_ws, size_t ws_size,
                              hipStream_t stream) {
    const float* ss  = (const float*)d_in[0]; // superclass_scores [B,S,H,W]
    const float* cs  = (const float*)d_in[1]; // class_score       [B,C,H,W]
    const float* w   = (const float*)d_in[2]; // weights [C]
    const int*   tgt = (const int*)d_in[3];   // target [B,H,W]
    const int*   s2s = (const int*)d_in[4];   // sub2super [C]

    float* outp = (float*)d_out;
    float* sums = (float*)d_ws;

    (void)hipMemsetAsync(sums, 0, NSUMS * sizeof(float), stream);
    fused_kernel<<<GRID, BLOCK, 0, stream>>>(ss, cs, tgt, s2s, outp, sums);
    loss_kernel<<<1, 64, 0, stream>>>(sums, w, outp);
}

// Round 10
// 86.215 us; speedup vs baseline: 1.4550x; 1.4550x over previous
//
#include <hip/hip_runtime.h>

#define SMOOTH_F 1e-7f

typedef float f32x4 __attribute__((ext_vector_type(4)));
typedef float f32x2 __attribute__((ext_vector_type(2)));

constexpr int B = 8, C = 12, S = 4, H = 512, W = 512;
constexpr int HW    = H * W;          // 262144 = 2^18
constexpr int NPIX  = B * HW;         // 2097152
constexpr int QUADS = NPIX / 4;       // 524288
constexpr int BLOCK = 256;
constexpr int GRID  = 1024;           // 2 quads/thread
constexpr int N     = B * C * HW;     // fc / oh element count

// q1 = q0 + GRID*BLOCK = q0 + 262144  ->  p1 = p0 + 4*HW, so rem1 == rem0 and
// b1 = b0 + 4: every q1 address is q0's address + a compile-time constant.
constexpr int DT  = 4 * HW;           // target offset between halves
constexpr int DSS = 4 * S * HW;       // superclass offset between halves
constexpr int DCS = 4 * C * HW;       // class offset between halves

// sums layout in d_ws (floats):
// [0..3]   interS   [4..7]  isumS   [8..11]  tsumS
// [12..23] interC   [24..35] isumC  [36..47] tsumC
constexpr int NSUMS = 48;

// lb note (R7/R8/R9 evidence): min-waves >= 6 flips the allocator into
// reg-minimization (VGPR 32-40) which serializes the channel loop and
// fragments NT write bursts (WRITE 202 -> 290+ MB). lb(256,2) gives the
// 2-quad batched schedule (~200 VGPR) full headroom.
__global__ __launch_bounds__(BLOCK, 2) void fused_kernel(
    const float* __restrict__ ss,   // [B,S,H,W]
    const float* __restrict__ cs,   // [B,C,H,W]
    const int*   __restrict__ tgt,  // [B,H,W]
    const int*   __restrict__ s2s,  // [C]
    float* __restrict__ outp,       // raw d_out: [loss, fc(N), oh(N)]
    float* __restrict__ sums)       // [48]
{
    const int q    = blockIdx.x * BLOCK + threadIdx.x; // quad in first half
    const int p    = q << 2;
    const int b    = p >> 18;         // 0..3 (q1 batch = b+4)
    const int rem  = p & (HW - 1);
    const int lane = threadIdx.x & 63;
    const int wv   = threadIdx.x >> 6;

    // ================= phase 1: issue ALL loads =================
    const int4 t40 = *reinterpret_cast<const int4*>(tgt + p);
    const int4 t41 = *reinterpret_cast<const int4*>(tgt + p + DT);

    float ssv0[S][4], ssv1[S][4];
    #pragma unroll
    for (int s = 0; s < S; s++) {
        const int base = (b * S + s) * HW + rem;
        const float4 v0 = *reinterpret_cast<const float4*>(ss + base);
        const float4 v1 = *reinterpret_cast<const float4*>(ss + base + DSS);
        ssv0[s][0] = v0.x; ssv0[s][1] = v0.y; ssv0[s][2] = v0.z; ssv0[s][3] = v0.w;
        ssv1[s][0] = v1.x; ssv1[s][1] = v1.y; ssv1[s][2] = v1.z; ssv1[s][3] = v1.w;
    }

    float cv0[C][4], cv1[C][4];
    #pragma unroll
    for (int c = 0; c < C; c++) {
        const int base = (b * C + c) * HW + rem;
        const float4 v0 = *reinterpret_cast<const float4*>(cs + base);
        const float4 v1 = *reinterpret_cast<const float4*>(cs + base + DCS);
        cv0[c][0] = v0.x; cv0[c][1] = v0.y; cv0[c][2] = v0.z; cv0[c][3] = v0.w;
        cv1[c][0] = v1.x; cv1[c][1] = v1.y; cv1[c][2] = v1.z; cv1[c][3] = v1.w;
    }

    const int t0[4] = {t40.x, t40.y, t40.z, t40.w};
    const int t1[4] = {t41.x, t41.y, t41.z, t41.w};
    int st0[4], st1[4];
    #pragma unroll
    for (int i = 0; i < 4; i++) { st0[i] = s2s[t0[i]]; st1[i] = s2s[t1[i]]; }

    // ================= phase 2: superclass accumulation =================
    float interS[S], isumS[S];
    int   tS[S], tC[C];
    #pragma unroll
    for (int s = 0; s < S; s++) {
        isumS[s] = ssv0[s][0] + ssv0[s][1] + ssv0[s][2] + ssv0[s][3]
                 + ssv1[s][0] + ssv1[s][1] + ssv1[s][2] + ssv1[s][3];
        interS[s] = 0.f; tS[s] = 0;
        #pragma unroll
        for (int i = 0; i < 4; i++) {
            const bool m0 = (st0[i] == s);
            const bool m1 = (st1[i] == s);
            interS[s] += m0 ? ssv0[s][i] : 0.f;
            interS[s] += m1 ? ssv1[s][i] : 0.f;
            tS[s] += (int)__popcll(__ballot(m0));
            tS[s] += (int)__popcll(__ballot(m1));
        }
    }

    // ================= phase 3: block-edge exchange (both quads) =========
    __shared__ float edge[BLOCK / 64][C][4];   // {fc0,oh0,fc1,oh1}
    if (lane == 63) {
        #pragma unroll
        for (int c = 0; c < C; c++) {
            const int sup = s2s[c];
            const float sv30 = (sup == 0) ? ssv0[0][3]
                             : (sup == 1) ? ssv0[1][3]
                             : (sup == 2) ? ssv0[2][3]
                             :              ssv0[3][3];
            const float sv31 = (sup == 0) ? ssv1[0][3]
                             : (sup == 1) ? ssv1[1][3]
                             : (sup == 2) ? ssv1[2][3]
                             :              ssv1[3][3];
            edge[wv][c][0] = cv0[c][3] * sv30;
            edge[wv][c][1] = (t0[3] == c) ? 1.f : 0.f;
            edge[wv][c][2] = cv1[c][3] * sv31;
            edge[wv][c][3] = (t1[3] == c) ? 1.f : 0.f;
        }
    }
    __syncthreads();

    // ================= phase 4: per-channel compute + aligned NT stores ===
    // Shifted window (addresses = element+1 from the loss scalar): threads
    // 1..255 store dwordx4 at J (lead via shfl_up / edge LDS), thread 0
    // stores the 3 leading elements, thread 255 the trailing one. Per-channel
    // 63-store bursts keep NT write-combining at full lines (WRITE=202MB).
    float interC[C], isumC[C];
    #pragma unroll
    for (int c = 0; c < C; c++) {
        const int J0  = (b * C + c) * HW + rem;
        const int J1  = J0 + DCS;
        const int sup = s2s[c];
        isumC[c] = cv0[c][0] + cv0[c][1] + cv0[c][2] + cv0[c][3]
                 + cv1[c][0] + cv1[c][1] + cv1[c][2] + cv1[c][3];
        interC[c] = 0.f; tC[c] = 0;
        float fc0[4], oh0[4], fc1[4], oh1[4];
        #pragma unroll
        for (int i = 0; i < 4; i++) {
            const bool e0 = (t0[i] == c);
            const bool e1 = (t1[i] == c);
            const float sv0 = (sup == 0) ? ssv0[0][i]
                            : (sup == 1) ? ssv0[1][i]
                            : (sup == 2) ? ssv0[2][i]
                            :              ssv0[3][i];
            const float sv1 = (sup == 0) ? ssv1[0][i]
                            : (sup == 1) ? ssv1[1][i]
                            : (sup == 2) ? ssv1[2][i]
                            :              ssv1[3][i];
            oh0[i] = e0 ? 1.f : 0.f;
            oh1[i] = e1 ? 1.f : 0.f;
            fc0[i] = cv0[c][i] * sv0;
            fc1[i] = cv1[c][i] * sv1;
            interC[c] += e0 ? cv0[c][i] : 0.f;
            interC[c] += e1 ? cv1[c][i] : 0.f;
            tC[c] += (int)__popcll(__ballot(e0));
            tC[c] += (int)__popcll(__ballot(e1));
        }
        float pfc0 = __shfl_up(fc0[3], 1);
        float poh0 = __shfl_up(oh0[3], 1);
        float pfc1 = __shfl_up(fc1[3], 1);
        float poh1 = __shfl_up(oh1[3], 1);
        if (lane == 0 && wv > 0) {
            pfc0 = edge[wv - 1][c][0]; poh0 = edge[wv - 1][c][1];
            pfc1 = edge[wv - 1][c][2]; poh1 = edge[wv - 1][c][3];
        }

        if (threadIdx.x != 0) {
            __builtin_nontemporal_store((f32x4){pfc0, fc0[0], fc0[1], fc0[2]},
                                        reinterpret_cast<f32x4*>(outp + J0));
            __builtin_nontemporal_store((f32x4){poh0, oh0[0], oh0[1], oh0[2]},
                                        reinterpret_cast<f32x4*>(outp + N + J0));
            __builtin_nontemporal_store((f32x4){pfc1, fc1[0], fc1[1], fc1[2]},
                                        reinterpret_cast<f32x4*>(outp + J1));
            __builtin_nontemporal_store((f32x4){poh1, oh1[0], oh1[1], oh1[2]},
                                        reinterpret_cast<f32x4*>(outp + N + J1));
        } else {
            __builtin_nontemporal_store(fc0[0], outp + J0 + 1);
            __builtin_nontemporal_store((f32x2){fc0[1], fc0[2]}, reinterpret_cast<f32x2*>(outp + J0 + 2));
            __builtin_nontemporal_store(oh0[0], outp + N + J0 + 1);
            __builtin_nontemporal_store((f32x2){oh0[1], oh0[2]}, reinterpret_cast<f32x2*>(outp + N + J0 + 2));
            __builtin_nontemporal_store(fc1[0], outp + J1 + 1);
            __builtin_nontemporal_store((f32x2){fc1[1], fc1[2]}, reinterpret_cast<f32x2*>(outp + J1 + 2));
            __builtin_nontemporal_store(oh1[0], outp + N + J1 + 1);
            __builtin_nontemporal_store((f32x2){oh1[1], oh1[2]}, reinterpret_cast<f32x2*>(outp + N + J1 + 2));
        }
        if (threadIdx.x == BLOCK - 1) {
            __builtin_nontemporal_store(fc0[3], outp + J0 + 4);
            __builtin_nontemporal_store(oh0[3], outp + N + J0 + 4);
            __builtin_nontemporal_store(fc1[3], outp + J1 + 4);
            __builtin_nontemporal_store(oh1[3], outp + N + J1 + 4);
        }
    }

    // ================= phase 5: block reduction =================
    float vals[32];
    #pragma unroll
    for (int s = 0; s < S; s++) { vals[s] = interS[s]; vals[4 + s] = isumS[s]; }
    #pragma unroll
    for (int c = 0; c < C; c++) { vals[8 + c] = interC[c]; vals[20 + c] = isumC[c]; }

    __shared__ float red[BLOCK / 64][NSUMS];
    #pragma unroll
    for (int k = 0; k < 32; k++) {
        float v = vals[k];
        #pragma unroll
        for (int o = 32; o > 0; o >>= 1) v += __shfl_xor(v, o, 64);
        if (lane == 0) {
            const int idx = (k < 8) ? k : (k < 20) ? (12 + (k - 8)) : (24 + (k - 20));
            red[wv][idx] = v;
        }
    }
    if (lane == 0) {
        #pragma unroll
        for (int s = 0; s < S; s++) red[wv][8 + s]  = (float)tS[s];
        #pragma unroll
        for (int c = 0; c < C; c++) red[wv][36 + c] = (float)tC[c];
    }
    __syncthreads();
    if (threadIdx.x < NSUMS) {
        const float sblk = red[0][threadIdx.x] + red[1][threadIdx.x]
                         + red[2][threadIdx.x] + red[3][threadIdx.x];
        atomicAdd(&sums[threadIdx.x], sblk);
    }
}

__global__ void loss_kernel(const float* __restrict__ sums,
                            const float* __restrict__ w,
                            float* __restrict__ out)
{
    if (threadIdx.x == 0 && blockIdx.x == 0) {
        float superL = 0.f;
        #pragma unroll
        for (int s = 0; s < S; s++)
            superL += 1.f - (2.f * sums[s] + SMOOTH_F) / (sums[4 + s] + sums[8 + s] + SMOOTH_F);
        float finalL = 0.f, wsum = 0.f;
        #pragma unroll
        for (int c = 0; c < C; c++) {
            wsum   += w[c];
            finalL += w[c] * (1.f - (2.f * sums[12 + c] + SMOOTH_F) / (sums[24 + c] + sums[36 + c] + SMOOTH_F));
        }
        out[0] = 0.1f * superL / (float)S + finalL / wsum;
    }
}

extern "C" void kernel_launch(void* const* d_in, const int* in_sizes, int n_in,
                              void* d_out, int out_size, void* d_ws, size_t ws_size,
                              hipStream_t stream) {
    const float* ss  = (const float*)d_in[0]; // superclass_scores [B,S,H,W]
    const float* cs  = (const float*)d_in[1]; // class_score       [B,C,H,W]
    const float* w   = (const float*)d_in[2]; // weights [C]
    const int*   tgt = (const int*)d_in[3];   // target [B,H,W]
    const int*   s2s = (const int*)d_in[4];   // sub2super [C]

    float* outp = (float*)d_out;
    float* sums = (float*)d_ws;

    (void)hipMemsetAsync(sums, 0, NSUMS * sizeof(float), stream);
    fused_kernel<<<GRID, BLOCK, 0, stream>>>(ss, cs, tgt, s2s, outp, sums);
    loss_kernel<<<1, 64, 0, stream>>>(sums, w, outp);
}